// Round 16
// baseline (484.832 us; speedup 1.0000x reference)
//
#include <hip/hip_runtime.h>
#include <math.h>

#define BATCH 8
#define NPTS 4096
#define CHAN 128
#define KNN 16
#define SPLIT 4
#define WIN 1536               // sorted-window candidates per point
#define WQ (WIN / SPLIT)       // 384 per split-block
#define QCH (WQ / 4)           // 96 per thread (6 batches, 8-bit local idx)
#define WOFF 736               // wbase - winLo (pre-clamp); >=736-pos margin
#define PTILE 64               // points per block
#define EPC 24                 // slow-path survivor buffer capacity
#define MARGIN 0.02f           // >> fp32 error of d2_ref/dx^2 (~1e-4)

typedef unsigned long long u64;

// Monotone key: ascending u64 == (d2 ascending, orig idx ascending).
__device__ __forceinline__ u64 pack_key(float d2, int idx) {
  unsigned b = __float_as_uint(d2);
  b ^= (unsigned)((int)b >> 31) | 0x80000000u;  // order-preserving fp32 map
  return ((u64)b << 32) | (unsigned)idx;
}

// Inverse of the d2 map (high 32 bits of key -> float d2).
__device__ __forceinline__ float key_d2(u64 k) {
  unsigned m = (unsigned)(k >> 32);
  unsigned b = (m & 0x80000000u) ? (m ^ 0x80000000u) : ~m;
  return __int_as_float((int)b);
}

// Reference d2: inner = ((x0*y0 + x1*y1) + x2*y2) fp32 no-fma; d2 = (sq_n +
// sq_m) - 2*inner. Bit-exact vs JAX reference.
__device__ __forceinline__ float d2_ref(float4 q, float ppx, float ppy,
                                        float ppz, float psq) {
  float inner = __fadd_rn(__fadd_rn(__fmul_rn(ppx, q.x), __fmul_rn(ppy, q.y)),
                          __fmul_rn(ppz, q.z));
  return __fsub_rn(__fadd_rn(psq, q.w), __fmul_rn(2.0f, inner));
}

// ----- u64 compare-exchange machinery ---------------------------------------
__device__ __forceinline__ void ce_asc(u64& x, u64& y) {
  bool sw = y < x;
  u64 lo = sw ? y : x;
  u64 hi = sw ? x : y;
  x = lo;
  y = hi;
}

// Batcher merge-exchange sort of 16 u64 keys, ascending. 63 CE.
__device__ __forceinline__ void batcher_sort16_u64(u64 a[16]) {
#define CE(i, j) ce_asc(a[i], a[j])
  CE(0, 8); CE(1, 9); CE(2, 10); CE(3, 11);
  CE(4, 12); CE(5, 13); CE(6, 14); CE(7, 15);
  CE(0, 4); CE(1, 5); CE(2, 6); CE(3, 7);
  CE(8, 12); CE(9, 13); CE(10, 14); CE(11, 15);
  CE(4, 8); CE(5, 9); CE(6, 10); CE(7, 11);
  CE(0, 2); CE(1, 3); CE(4, 6); CE(5, 7);
  CE(8, 10); CE(9, 11); CE(12, 14); CE(13, 15);
  CE(2, 8); CE(3, 9); CE(6, 12); CE(7, 13);
  CE(2, 4); CE(3, 5); CE(6, 8); CE(7, 9); CE(10, 12); CE(11, 13);
  CE(0, 1); CE(2, 3); CE(4, 5); CE(6, 7);
  CE(8, 9); CE(10, 11); CE(12, 13); CE(14, 15);
  CE(1, 8); CE(3, 10); CE(5, 12); CE(7, 14);
  CE(1, 4); CE(3, 6); CE(5, 8); CE(7, 10); CE(9, 12); CE(11, 14);
  CE(1, 2); CE(3, 4); CE(5, 6); CE(7, 8); CE(9, 10); CE(11, 12); CE(13, 14);
#undef CE
}

// Bitonic sort of 32 u64 keys, ascending. (slow path only)
__device__ __forceinline__ void bitonic_sort32(u64 a[32]) {
#pragma unroll
  for (int k = 2; k <= 32; k <<= 1) {
#pragma unroll
    for (int j = k >> 1; j > 0; j >>= 1) {
#pragma unroll
      for (int i = 0; i < 32; ++i) {
        int l = i ^ j;
        if (l > i) {
          if ((i & k) == 0) ce_asc(a[i], a[l]);
          else              ce_asc(a[l], a[i]);
        }
      }
    }
  }
}

// T, A both sorted ascending. T <- lowest-16 of (T ∪ A), sorted ascending.
__device__ __forceinline__ void merge_keep16(u64 T[16], const u64 A[16]) {
  u64 nt[16];
#pragma unroll
  for (int i = 0; i < 16; ++i) {
    u64 a = A[15 - i];
    nt[i] = (a < T[i]) ? a : T[i];
  }
#pragma unroll
  for (int j = 8; j > 0; j >>= 1) {
#pragma unroll
    for (int i = 0; i < 16; ++i) {
      int l = i ^ j;
      if (l > i) ce_asc(nt[i], nt[l]);
    }
  }
#pragma unroll
  for (int i = 0; i < 16; ++i) T[i] = nt[i];
}

// ----- i32 packed-key machinery (hot phase 1; proven R3-R13) ---------------
__device__ __forceinline__ void ce_i32(int& x, int& y) {
  int lo = min(x, y);
  int hi = max(x, y);
  x = lo;
  y = hi;
}

__device__ __forceinline__ void batcher_sort16_i32(int a[16]) {
#define CE(i, j) ce_i32(a[i], a[j])
  CE(0, 8); CE(1, 9); CE(2, 10); CE(3, 11);
  CE(4, 12); CE(5, 13); CE(6, 14); CE(7, 15);
  CE(0, 4); CE(1, 5); CE(2, 6); CE(3, 7);
  CE(8, 12); CE(9, 13); CE(10, 14); CE(11, 15);
  CE(4, 8); CE(5, 9); CE(6, 10); CE(7, 11);
  CE(0, 2); CE(1, 3); CE(4, 6); CE(5, 7);
  CE(8, 10); CE(9, 11); CE(12, 14); CE(13, 15);
  CE(2, 8); CE(3, 9); CE(6, 12); CE(7, 13);
  CE(2, 4); CE(3, 5); CE(6, 8); CE(7, 9); CE(10, 12); CE(11, 13);
  CE(0, 1); CE(2, 3); CE(4, 5); CE(6, 7);
  CE(8, 9); CE(10, 11); CE(12, 13); CE(14, 15);
  CE(1, 8); CE(3, 10); CE(5, 12); CE(7, 14);
  CE(1, 4); CE(3, 6); CE(5, 8); CE(7, 10); CE(9, 12); CE(11, 14);
  CE(1, 2); CE(3, 4); CE(5, 6); CE(7, 8); CE(9, 10); CE(11, 12); CE(13, 14);
#undef CE
}

__device__ __forceinline__ void merge_keep16_i32(int T[16], const int A[16]) {
  int nt[16];
#pragma unroll
  for (int i = 0; i < 16; ++i) nt[i] = min(A[15 - i], T[i]);
#pragma unroll
  for (int j = 8; j > 0; j >>= 1) {
#pragma unroll
    for (int i = 0; i < 16; ++i) {
      int l = i ^ j;
      if (l > i) ce_i32(nt[i], nt[l]);
    }
  }
#pragma unroll
  for (int i = 0; i < 16; ++i) T[i] = nt[i];
}

// window base for sorted position range [wbase, wbase+64)
__device__ __forceinline__ int win_lo(int wbase) {
  int lo = wbase - WOFF;
  if (lo < 0) lo = 0;
  if (lo > NPTS - WIN) lo = NPTS - WIN;
  return lo;
}

// ---------------------------------------------------------------------------
// Kernel 0 (pack + x-sort, fused; R15-proven): counting-rank by (x, idx)
// ascending -> scatter (x,y,z,sq) into sorted order + sorted->orig map.
// Also zeroes flagcnt (runs before any reader, every replay).
// grid: BATCH*(NPTS/64) = 512 blocks.
// ---------------------------------------------------------------------------
__global__ __launch_bounds__(256) void xsort_kernel(
    const float* __restrict__ x, float4* __restrict__ spacked,
    int* __restrict__ soidx, int* __restrict__ flagcnt) {
  if (blockIdx.x == 0 && threadIdx.x == 0) *flagcnt = 0;
  const int tile = blockIdx.x % (NPTS / 64);
  const int b = blockIdx.x / (NPTS / 64);
  const int g = threadIdx.x >> 2;  // point within tile [0,64)
  const int s = threadIdx.x & 3;   // quarter
  __shared__ float4 xv[NPTS / 4];  // 16 KB (x-plane of the batch)

  const float* xb = x + (size_t)b * 3 * NPTS;
  const float4* xb4 = reinterpret_cast<const float4*>(xb);
  for (int i = threadIdx.x; i < NPTS / 4; i += 256) xv[i] = xb4[i];
  const int n = tile * 64 + g;
  const float xn = xb[n];
  __syncthreads();

  int c = 0;
  const int v0 = s * (NPTS / 16);
#pragma unroll 4
  for (int v = v0; v < v0 + NPTS / 16; ++v) {
    float4 f = xv[v];
    int gm = 4 * v;
    c += (f.x < xn) || (f.x == xn && gm < n);
    c += (f.y < xn) || (f.y == xn && gm + 1 < n);
    c += (f.z < xn) || (f.z == xn && gm + 2 < n);
    c += (f.w < xn) || (f.w == xn && gm + 3 < n);
  }
  c += __shfl_xor(c, 1);
  c += __shfl_xor(c, 2);  // full rank on all 4 lanes
  if (s == 0) {
    float px = xn;
    float py = xb[NPTS + n];
    float pz = xb[2 * NPTS + n];
    float sq = __fadd_rn(__fadd_rn(__fmul_rn(px, px), __fmul_rn(py, py)),
                         __fmul_rn(pz, pz));
    spacked[(size_t)b * NPTS + c] = make_float4(px, py, pz, sq);
    soidx[(size_t)b * NPTS + c] = n;
  }
}

// ---------------------------------------------------------------------------
// Kernel 1a: windowed 16-NN partials (R12's proven uniform-load kernel,
// retargeted at a 1536-cand sorted window; per-thread 256 -> 96 cands).
// R15 lesson: per-lane gathers are L1-BW-bound (64x bytes/inst vs uniform
// broadcast) -- so the window scan keeps WAVE-UNIFORM candidate addresses.
// Keys carry ORIGINAL indices (via soidx) -> downstream tie-break exact.
// grid: B x (N/64) x SPLIT = 2048 blocks x 256 thr = 8192 waves (as R12).
// Exactness: within-window top-16 exact (8-bit trunc + r17 guard + exact
// epilogue, proven R3-R13); window sufficiency checked in merge_score via
// the R14/R15-validated slab test; failures routed to fixup_kernel.
// ---------------------------------------------------------------------------
__global__ __launch_bounds__(256) void knn_partial_kernel(
    const float4* __restrict__ spacked, const int* __restrict__ soidx,
    u64* __restrict__ pkey) {
  const int s = blockIdx.x % SPLIT;
  const int ntile = (blockIdx.x / SPLIT) % (NPTS / PTILE);
  const int b = blockIdx.x / (SPLIT * (NPTS / PTILE));
  const int p = threadIdx.x & (PTILE - 1);
  const int q4 = threadIdx.x >> 6;  // quarter 0..3 == wave id
  __shared__ u64 ubuf[1024];        // 8 KB: u8 scratch(6K) ∪ staging[16][64]

  const float4* sp4 = spacked + (size_t)b * NPTS;
  const int* sid = soidx + (size_t)b * NPTS;
  const int wbase = ntile * PTILE;
  const int pos = wbase + p;
  float4 pp = sp4[pos];
  const float ppx = pp.x, ppy = pp.y, ppz = pp.z, psq = pp.w;

  // wave-uniform candidate sub-window base
  const int qLo =
      __builtin_amdgcn_readfirstlane(win_lo(wbase) + s * WQ + q4 * QCH);
  const float4* win = sp4 + qLo;
  const int* wid = sid + qLo;

  // ---- Phase 1: top-16 packed keys + exact 17th (r17) ----
  int T[16];
#pragma unroll
  for (int i = 0; i < 16; ++i) T[i] = 0x7FFFFFFF;  // sentinel > any real key
  int r17 = 0x7FFFFFFF;

#pragma unroll 1
  for (int base = 0; base < QCH; base += 16) {
    int A[16];
#pragma unroll
    for (int t = 0; t < 16; ++t) {
      float4 q = win[base + t];  // uniform addr -> broadcast
      int bits = __float_as_int(d2_ref(q, ppx, ppy, ppz, psq));
      A[t] = (bits & 0xFFFFFF00) | (base + t);
    }
    batcher_sort16_i32(A);
    int u[16];
#pragma unroll
    for (int i = 0; i < 16; ++i) u[i] = max(T[i], A[15 - i]);
#pragma unroll
    for (int w = 8; w > 0; w >>= 1) {
#pragma unroll
      for (int i = 0; i < 16; ++i) {
        if (i < w) u[i] = min(u[i], u[i + w]);
      }
    }
    r17 = min(r17, u[0]);
    merge_keep16_i32(T, A);
  }

  const int tau = T[15] & 0xFFFFFF00;
  const bool slow = ((r17 & 0xFFFFFF00) == tau);

  // ---- Epilogue: exact u64 top-16 keys (original indices) ----
  u64 K[16];
  if (!slow) {
#pragma unroll
    for (int j = 0; j < 16; ++j) {
      int loc = T[j] & 255;  // < QCH
      float4 q = win[loc];
      float d2 = d2_ref(q, ppx, ppy, ppz, psq);
      K[j] = pack_key(d2, wid[loc]);
    }
    batcher_sort16_u64(K);
  } else {
    unsigned char* myb =
        reinterpret_cast<unsigned char*>(ubuf) + (unsigned)threadIdx.x * EPC;
    int cnt = 0;
#pragma unroll 4
    for (int m = 0; m < QCH; ++m) {
      float4 q = win[m];  // uniform
      int tb = __float_as_int(d2_ref(q, ppx, ppy, ppz, psq)) & 0xFFFFFF00;
      if (tb <= tau) {
        myb[cnt < EPC - 1 ? cnt : EPC - 1] = (unsigned char)m;
        ++cnt;
      }
    }
    u64 KK[32];
#pragma unroll
    for (int j = 0; j < EPC; ++j) {
      int loc = min((int)myb[j], QCH - 1);
      float4 q = win[loc];
      float d2 = d2_ref(q, ppx, ppy, ppz, psq);
      u64 k = pack_key(d2, wid[loc]);
      KK[j] = (j < cnt) ? k : ~0ull;
    }
#pragma unroll
    for (int j = EPC; j < 32; ++j) KK[j] = ~0ull;
    bitonic_sort32(KK);
#pragma unroll
    for (int j = 0; j < 16; ++j) K[j] = KK[j];
  }

  // ---- combine quarters: chain q1,q2,q3 stage -> q0 merges (R12-proven) ----
  __syncthreads();
  u64(*L)[PTILE] = reinterpret_cast<u64(*)[PTILE]>(ubuf);  // [16][64]
#pragma unroll 1
  for (int r = 1; r <= 3; ++r) {
    if (q4 == r) {
#pragma unroll
      for (int j = 0; j < 16; ++j) L[j][p] = K[j];
    }
    __syncthreads();
    if (q4 == 0) {
      u64 A64[16];
#pragma unroll
      for (int j = 0; j < 16; ++j) A64[j] = L[j][p];
      merge_keep16(K, A64);
    }
    __syncthreads();
  }
  if (q4 == 0) {
    u64* pb = pkey + ((size_t)(b * SPLIT + s) * KNN) * NPTS + pos;
#pragma unroll
    for (int j = 0; j < 16; ++j) pb[(size_t)j * NPTS] = K[j];
  }
}

// ---------------------------------------------------------------------------
// Kernel 1b: merge SPLIT window-quarter lists -> window top-16, slab-check
// the window boundaries (R14/R15-validated exactness test), flag failures,
// score. R10/R12's proven 4-threads-per-point form. n = SORTED position.
// grid: BATCH*(NPTS/64) = 512 blocks x 256.
// ---------------------------------------------------------------------------
__global__ __launch_bounds__(256) void merge_score_kernel(
    const float* __restrict__ x, const float4* __restrict__ spacked,
    const int* __restrict__ soidx, const u64* __restrict__ pkey,
    float* __restrict__ score, int* __restrict__ flagcnt,
    int* __restrict__ flaglist) {
  const int tile = blockIdx.x % (NPTS / 64);
  const int b = blockIdx.x / (NPTS / 64);
  const int g = threadIdx.x >> 2;  // point within tile [0,64)
  const int s = threadIdx.x & 3;   // split list
  const int n = tile * 64 + g;     // sorted position

  u64 T[16];
  {
    const u64* pb = pkey + ((size_t)(b * SPLIT + s) * KNN) * NPTS + n;
#pragma unroll
    for (int j = 0; j < 16; ++j) T[j] = pb[(size_t)j * NPTS];
  }
  u64 A[16];
#pragma unroll
  for (int j = 0; j < 16; ++j) A[j] = (u64)__shfl_xor((long long)T[j], 1);
  merge_keep16(T, A);
#pragma unroll
  for (int j = 0; j < 16; ++j) A[j] = (u64)__shfl_xor((long long)T[j], 2);
  merge_keep16(T, A);
  // all 4 lanes hold the window's sorted top-16 (exact, original indices).

  const float4* sp4 = spacked + (size_t)b * NPTS;
  const int orig = soidx[(size_t)b * NPTS + n];

  // ---- window-sufficiency slab test (exact; see R14/R15 proof) ----
  const int wlo = win_lo(n & ~(PTILE - 1));
  const int whi = wlo + WIN;
  const float xn = sp4[n].x;
  const float bnd = key_d2(T[15]);
  bool safe = true;
  if (wlo > 0) {
    float dx = xn - sp4[wlo - 1].x;  // >= 0 (sorted)
    safe = safe && (dx * dx > bnd + MARGIN);
  }
  if (whi < NPTS) {
    float dx = sp4[whi].x - xn;  // >= 0
    safe = safe && (dx * dx > bnd + MARGIN);
  }
  if (!safe && s == 0) {
    int idx = atomicAdd(flagcnt, 1);
    flaglist[idx] = (b << 12) | n;
  }

  // ---- score (numpy pairwise; lanes 0..2 own dims; recombine) ----
  const float* xb = x + (size_t)b * 3 * NPTS;
  float P = 0.0f;
  if (s < 3) {
    const float* xd = xb + (size_t)s * NPTS;
    const float pc = xd[orig];
    float r[8];
#pragma unroll
    for (int j = 0; j < 8; ++j) {
      float c0 = xd[(int)(unsigned)T[j]];
      float c1 = xd[(int)(unsigned)T[j + 8]];
      float e0 = __fsub_rn(c0, pc);
      float e1 = __fsub_rn(c1, pc);
      r[j] = __fadd_rn(__fmul_rn(e0, e0), __fmul_rn(e1, e1));
    }
    float t0 = __fadd_rn(r[0], r[1]);
    float t1 = __fadd_rn(r[2], r[3]);
    float t2 = __fadd_rn(r[4], r[5]);
    float t3 = __fadd_rn(r[6], r[7]);
    P = __fadd_rn(__fadd_rn(t0, t1), __fadd_rn(t2, t3));
  }
  float Pa = __shfl_xor(P, 1);
  float Pb = __shfl_xor(P, 2);
  if (s == 0)
    score[(size_t)b * NPTS + orig] = __fadd_rn(__fadd_rn(P, Pa), Pb);
}

// ---------------------------------------------------------------------------
// Kernel 1c (fixup, expected empty): one WAVE per flagged point does an
// exact full-batch scan (64 lanes x 64 cands, exact u64 keys) + log-merge,
// then lane 0 rescores and overwrites. Correct for any flag pattern.
// grid: 64 blocks x 256 thr = 256 waves, stride loop over flagcnt.
// ---------------------------------------------------------------------------
__global__ __launch_bounds__(256) void fixup_kernel(
    const float* __restrict__ x, const float4* __restrict__ spacked,
    const int* __restrict__ soidx, const int* __restrict__ flagcnt,
    const int* __restrict__ flaglist, float* __restrict__ score) {
  const int wave = (blockIdx.x * 256 + threadIdx.x) >> 6;
  const int lane = threadIdx.x & 63;
  const int cnt = *flagcnt;
#pragma unroll 1
  for (int i = wave; i < cnt; i += 256) {
    int e = flaglist[i];
    int b = e >> 12;
    int pos = e & (NPTS - 1);
    const float4* sp4 = spacked + (size_t)b * NPTS;
    const int* sid = soidx + (size_t)b * NPTS;
    float4 pp = sp4[pos];
    const float ppx = pp.x, ppy = pp.y, ppz = pp.z, psq = pp.w;

    u64 T[16];
#pragma unroll
    for (int j = 0; j < 16; ++j) T[j] = ~0ull;
#pragma unroll 1
    for (int k = 0; k < 4; ++k) {
      int s0 = lane * 16 + k * 1024;  // all 4096 covered exactly once
      u64 A[16];
#pragma unroll
      for (int t = 0; t < 16; ++t) {
        float4 q = sp4[s0 + t];
        float d2 = d2_ref(q, ppx, ppy, ppz, psq);
        A[t] = pack_key(d2, sid[s0 + t]);
      }
      batcher_sort16_u64(A);
      merge_keep16(T, A);
    }
#pragma unroll
    for (int m = 1; m <= 32; m <<= 1) {
      u64 A[16];
#pragma unroll
      for (int j = 0; j < 16; ++j) A[j] = (u64)__shfl_xor((long long)T[j], m);
      merge_keep16(T, A);
    }
    if (lane == 0) {
      const float* xb = x + (size_t)b * 3 * NPTS;
      const int orig = sid[pos];
      float P[3];
#pragma unroll
      for (int d = 0; d < 3; ++d) {
        const float* xd = xb + (size_t)d * NPTS;
        const float pc = xd[orig];
        float r[8];
#pragma unroll
        for (int j = 0; j < 8; ++j) {
          float c0 = xd[(int)(unsigned)T[j]];
          float c1 = xd[(int)(unsigned)T[j + 8]];
          float e0 = __fsub_rn(c0, pc);
          float e1 = __fsub_rn(c1, pc);
          r[j] = __fadd_rn(__fmul_rn(e0, e0), __fmul_rn(e1, e1));
        }
        float t0 = __fadd_rn(r[0], r[1]);
        float t1 = __fadd_rn(r[2], r[3]);
        float t2 = __fadd_rn(r[4], r[5]);
        float t3 = __fadd_rn(r[6], r[7]);
        P[d] = __fadd_rn(__fadd_rn(t0, t1), __fadd_rn(t2, t3));
      }
      score[(size_t)b * NPTS + orig] =
          __fadd_rn(__fadd_rn(P[0], P[1]), P[2]);
    }
  }
}

// ---------------------------------------------------------------------------
// Kernel 2 (fused rank + scatter, atomics-free; R11-proven).
// grid: BATCH*(NPTS/128) = 256 blocks.
// ---------------------------------------------------------------------------
__global__ __launch_bounds__(256) void rank_scatter_kernel(
    const float* __restrict__ score, int* __restrict__ sel, int npts) {
  const int tile = blockIdx.x % (NPTS / 128);
  const int b = blockIdx.x / (NPTS / 128);
  const int p = threadIdx.x & 127;
  const int h = threadIdx.x >> 7;
  __shared__ float4 sv[NPTS / 4];  // 16 KB
  __shared__ int cpart[128];

  const float* sb = score + (size_t)b * NPTS;
  const float4* sb4 = reinterpret_cast<const float4*>(sb);
  for (int i = threadIdx.x; i < NPTS / 4; i += 256) sv[i] = sb4[i];

  const int n = tile * 128 + p;
  const float sn = sb[n];
  __syncthreads();

  int c = 0;
  const int v0 = h * (NPTS / 8);
#pragma unroll 4
  for (int v = v0; v < v0 + NPTS / 8; ++v) {
    float4 f = sv[v];
    int gm = 4 * v;
    c += (f.x > sn) || (f.x == sn && gm < n);
    c += (f.y > sn) || (f.y == sn && gm + 1 < n);
    c += (f.z > sn) || (f.z == sn && gm + 2 < n);
    c += (f.w > sn) || (f.w == sn && gm + 3 < n);
  }
  if (h == 1) cpart[p] = c;
  __syncthreads();
  if (h == 0) {
    c += cpart[p];
    if (c < npts) sel[(size_t)b * npts + c] = n;
  }
}

// ---------------------------------------------------------------------------
// Kernel 3: gather xyz then features into the concatenated flat output.
// ---------------------------------------------------------------------------
__global__ __launch_bounds__(256) void gather_kernel(
    const float* __restrict__ x, const float* __restrict__ y,
    const int* __restrict__ sel, float* __restrict__ out, int npts,
    int total0, int total) {
  int tid = blockIdx.x * blockDim.x + threadIdx.x;
  if (tid >= total) return;
  if (tid < total0) {
    int j = tid % npts;
    int rest = tid / npts;
    int d = rest % 3;
    int b = rest / 3;
    int src = sel[b * npts + j];
    out[tid] = x[((size_t)b * 3 + d) * NPTS + src];
  } else {
    int t = tid - total0;
    int j = t % npts;
    int rest = t / npts;
    int c = rest % CHAN;
    int b = rest / CHAN;
    int src = sel[b * npts + j];
    out[tid] = y[((size_t)b * CHAN + c) * NPTS + src];
  }
}

extern "C" void kernel_launch(void* const* d_in, const int* in_sizes, int n_in,
                              void* d_out, int out_size, void* d_ws,
                              size_t ws_size, hipStream_t stream) {
  const float* x = (const float*)d_in[0];
  const float* y = (const float*)d_in[1];
  float* out = (float*)d_out;

  const int npts = out_size / (BATCH * (3 + CHAN));

  // workspace layout (~19.3 MB; 19 MB fit in R13):
  char* w = (char*)d_ws;
  float4* spacked = (float4*)w;              // B*N float4 = 2 MB (x-sorted)
  w += sizeof(float4) * (size_t)BATCH * NPTS;
  int* soidx = (int*)w;                      // B*N i32 (sorted -> original)
  w += sizeof(int) * (size_t)BATCH * NPTS;
  u64* pkey = (u64*)w;                       // B*S*16*N u64 = 16.78 MB
  w += sizeof(u64) * (size_t)BATCH * SPLIT * KNN * NPTS;
  float* score = (float*)w;                  // B*N f32
  w += sizeof(float) * (size_t)BATCH * NPTS;
  int* flagcnt = (int*)w;                    // 1 i32 (+ pad)
  w += 256;
  int* flaglist = (int*)w;                   // B*N i32 worst case
  w += sizeof(int) * (size_t)BATCH * NPTS;
  int* sel = (int*)w;                        // B*npts i32

  xsort_kernel<<<BATCH * (NPTS / 64), 256, 0, stream>>>(x, spacked, soidx,
                                                        flagcnt);
  knn_partial_kernel<<<BATCH * (NPTS / PTILE) * SPLIT, 256, 0, stream>>>(
      spacked, soidx, pkey);
  merge_score_kernel<<<BATCH * (NPTS / 64), 256, 0, stream>>>(
      x, spacked, soidx, pkey, score, flagcnt, flaglist);
  fixup_kernel<<<64, 256, 0, stream>>>(x, spacked, soidx, flagcnt, flaglist,
                                       score);
  rank_scatter_kernel<<<BATCH * (NPTS / 128), 256, 0, stream>>>(score, sel,
                                                                npts);
  const int total0 = BATCH * 3 * npts;
  gather_kernel<<<(out_size + 255) / 256, 256, 0, stream>>>(
      x, y, sel, out, npts, total0, out_size);
}

// Round 18
// 295.969 us; speedup vs baseline: 1.6381x; 1.6381x over previous
//
#include <hip/hip_runtime.h>
#include <math.h>

#define BATCH 8
#define NPTS 4096
#define CHAN 128
#define KNN 16
#define SPLIT 4
#define WIN 1536               // sorted-window candidates per point
#define WQ (WIN / SPLIT)       // 384 per split-block
#define QCH (WQ / 4)           // 96 per thread (6 batches, 8-bit local idx)
#define WOFF 736               // wbase - winLo (pre-clamp); >=736-pos margin
#define PTILE 64               // points per block
#define EPC 24                 // slow-path survivor buffer capacity
#define MARGIN 0.02f           // >> fp32 error of d2_ref/dx^2 (~1e-4)
#define FIXBLK 1024            // fixup grid (R16 lesson: 64 blocks starved it)

typedef unsigned long long u64;

// Monotone key: ascending u64 == (d2 ascending, orig idx ascending).
__device__ __forceinline__ u64 pack_key(float d2, int idx) {
  unsigned b = __float_as_uint(d2);
  b ^= (unsigned)((int)b >> 31) | 0x80000000u;  // order-preserving fp32 map
  return ((u64)b << 32) | (unsigned)idx;
}

// Inverse of the d2 map (high 32 bits of key -> float d2).
__device__ __forceinline__ float key_d2(u64 k) {
  unsigned m = (unsigned)(k >> 32);
  unsigned b = (m & 0x80000000u) ? (m ^ 0x80000000u) : ~m;
  return __int_as_float((int)b);
}

// Reference d2: inner = ((x0*y0 + x1*y1) + x2*y2) fp32 no-fma; d2 = (sq_n +
// sq_m) - 2*inner. Bit-exact vs JAX reference.
__device__ __forceinline__ float d2_ref(float4 q, float ppx, float ppy,
                                        float ppz, float psq) {
  float inner = __fadd_rn(__fadd_rn(__fmul_rn(ppx, q.x), __fmul_rn(ppy, q.y)),
                          __fmul_rn(ppz, q.z));
  return __fsub_rn(__fadd_rn(psq, q.w), __fmul_rn(2.0f, inner));
}

// ----- u64 compare-exchange machinery ---------------------------------------
__device__ __forceinline__ void ce_asc(u64& x, u64& y) {
  bool sw = y < x;
  u64 lo = sw ? y : x;
  u64 hi = sw ? x : y;
  x = lo;
  y = hi;
}

// Batcher merge-exchange sort of 16 u64 keys, ascending. 63 CE.
__device__ __forceinline__ void batcher_sort16_u64(u64 a[16]) {
#define CE(i, j) ce_asc(a[i], a[j])
  CE(0, 8); CE(1, 9); CE(2, 10); CE(3, 11);
  CE(4, 12); CE(5, 13); CE(6, 14); CE(7, 15);
  CE(0, 4); CE(1, 5); CE(2, 6); CE(3, 7);
  CE(8, 12); CE(9, 13); CE(10, 14); CE(11, 15);
  CE(4, 8); CE(5, 9); CE(6, 10); CE(7, 11);
  CE(0, 2); CE(1, 3); CE(4, 6); CE(5, 7);
  CE(8, 10); CE(9, 11); CE(12, 14); CE(13, 15);
  CE(2, 8); CE(3, 9); CE(6, 12); CE(7, 13);
  CE(2, 4); CE(3, 5); CE(6, 8); CE(7, 9); CE(10, 12); CE(11, 13);
  CE(0, 1); CE(2, 3); CE(4, 5); CE(6, 7);
  CE(8, 9); CE(10, 11); CE(12, 13); CE(14, 15);
  CE(1, 8); CE(3, 10); CE(5, 12); CE(7, 14);
  CE(1, 4); CE(3, 6); CE(5, 8); CE(7, 10); CE(9, 12); CE(11, 14);
  CE(1, 2); CE(3, 4); CE(5, 6); CE(7, 8); CE(9, 10); CE(11, 12); CE(13, 14);
#undef CE
}

// Bitonic sort of 32 u64 keys, ascending. (slow path only)
__device__ __forceinline__ void bitonic_sort32(u64 a[32]) {
#pragma unroll
  for (int k = 2; k <= 32; k <<= 1) {
#pragma unroll
    for (int j = k >> 1; j > 0; j >>= 1) {
#pragma unroll
      for (int i = 0; i < 32; ++i) {
        int l = i ^ j;
        if (l > i) {
          if ((i & k) == 0) ce_asc(a[i], a[l]);
          else              ce_asc(a[l], a[i]);
        }
      }
    }
  }
}

// T, A both sorted ascending. T <- lowest-16 of (T ∪ A), sorted ascending.
__device__ __forceinline__ void merge_keep16(u64 T[16], const u64 A[16]) {
  u64 nt[16];
#pragma unroll
  for (int i = 0; i < 16; ++i) {
    u64 a = A[15 - i];
    nt[i] = (a < T[i]) ? a : T[i];
  }
#pragma unroll
  for (int j = 8; j > 0; j >>= 1) {
#pragma unroll
    for (int i = 0; i < 16; ++i) {
      int l = i ^ j;
      if (l > i) ce_asc(nt[i], nt[l]);
    }
  }
#pragma unroll
  for (int i = 0; i < 16; ++i) T[i] = nt[i];
}

// ----- i32 packed-key machinery (hot phase 1; proven R3-R13) ---------------
__device__ __forceinline__ void ce_i32(int& x, int& y) {
  int lo = min(x, y);
  int hi = max(x, y);
  x = lo;
  y = hi;
}

__device__ __forceinline__ void batcher_sort16_i32(int a[16]) {
#define CE(i, j) ce_i32(a[i], a[j])
  CE(0, 8); CE(1, 9); CE(2, 10); CE(3, 11);
  CE(4, 12); CE(5, 13); CE(6, 14); CE(7, 15);
  CE(0, 4); CE(1, 5); CE(2, 6); CE(3, 7);
  CE(8, 12); CE(9, 13); CE(10, 14); CE(11, 15);
  CE(4, 8); CE(5, 9); CE(6, 10); CE(7, 11);
  CE(0, 2); CE(1, 3); CE(4, 6); CE(5, 7);
  CE(8, 10); CE(9, 11); CE(12, 14); CE(13, 15);
  CE(2, 8); CE(3, 9); CE(6, 12); CE(7, 13);
  CE(2, 4); CE(3, 5); CE(6, 8); CE(7, 9); CE(10, 12); CE(11, 13);
  CE(0, 1); CE(2, 3); CE(4, 5); CE(6, 7);
  CE(8, 9); CE(10, 11); CE(12, 13); CE(14, 15);
  CE(1, 8); CE(3, 10); CE(5, 12); CE(7, 14);
  CE(1, 4); CE(3, 6); CE(5, 8); CE(7, 10); CE(9, 12); CE(11, 14);
  CE(1, 2); CE(3, 4); CE(5, 6); CE(7, 8); CE(9, 10); CE(11, 12); CE(13, 14);
#undef CE
}

__device__ __forceinline__ void merge_keep16_i32(int T[16], const int A[16]) {
  int nt[16];
#pragma unroll
  for (int i = 0; i < 16; ++i) nt[i] = min(A[15 - i], T[i]);
#pragma unroll
  for (int j = 8; j > 0; j >>= 1) {
#pragma unroll
    for (int i = 0; i < 16; ++i) {
      int l = i ^ j;
      if (l > i) ce_i32(nt[i], nt[l]);
    }
  }
#pragma unroll
  for (int i = 0; i < 16; ++i) T[i] = nt[i];
}

// window base for sorted position range [wbase, wbase+64)
__device__ __forceinline__ int win_lo(int wbase) {
  int lo = wbase - WOFF;
  if (lo < 0) lo = 0;
  if (lo > NPTS - WIN) lo = NPTS - WIN;
  return lo;
}

// ---------------------------------------------------------------------------
// Kernel 0 (pack + x-sort, fused; R15-proven): counting-rank by (x, idx)
// ascending -> scatter (x,y,z,sq) into sorted order + sorted->orig map.
// Also zeroes flagcnt (runs before any reader, every replay).
// grid: BATCH*(NPTS/64) = 512 blocks.
// ---------------------------------------------------------------------------
__global__ __launch_bounds__(256) void xsort_kernel(
    const float* __restrict__ x, float4* __restrict__ spacked,
    int* __restrict__ soidx, int* __restrict__ flagcnt) {
  if (blockIdx.x == 0 && threadIdx.x == 0) *flagcnt = 0;
  const int tile = blockIdx.x % (NPTS / 64);
  const int b = blockIdx.x / (NPTS / 64);
  const int g = threadIdx.x >> 2;  // point within tile [0,64)
  const int s = threadIdx.x & 3;   // quarter
  __shared__ float4 xv[NPTS / 4];  // 16 KB (x-plane of the batch)

  const float* xb = x + (size_t)b * 3 * NPTS;
  const float4* xb4 = reinterpret_cast<const float4*>(xb);
  for (int i = threadIdx.x; i < NPTS / 4; i += 256) xv[i] = xb4[i];
  const int n = tile * 64 + g;
  const float xn = xb[n];
  __syncthreads();

  int c = 0;
  const int v0 = s * (NPTS / 16);
#pragma unroll 4
  for (int v = v0; v < v0 + NPTS / 16; ++v) {
    float4 f = xv[v];
    int gm = 4 * v;
    c += (f.x < xn) || (f.x == xn && gm < n);
    c += (f.y < xn) || (f.y == xn && gm + 1 < n);
    c += (f.z < xn) || (f.z == xn && gm + 2 < n);
    c += (f.w < xn) || (f.w == xn && gm + 3 < n);
  }
  c += __shfl_xor(c, 1);
  c += __shfl_xor(c, 2);  // full rank on all 4 lanes
  if (s == 0) {
    float px = xn;
    float py = xb[NPTS + n];
    float pz = xb[2 * NPTS + n];
    float sq = __fadd_rn(__fadd_rn(__fmul_rn(px, px), __fmul_rn(py, py)),
                         __fmul_rn(pz, pz));
    spacked[(size_t)b * NPTS + c] = make_float4(px, py, pz, sq);
    soidx[(size_t)b * NPTS + c] = n;
  }
}

// ---------------------------------------------------------------------------
// Kernel 1a: windowed 16-NN partials (R12's proven uniform-load kernel over
// a 1536-cand sorted window; per-thread 96 cands). Wave-uniform candidate
// addresses (R15 lesson: per-lane gathers are L1-BW-bound).
// grid: B x (N/64) x SPLIT = 2048 blocks x 256 thr = 8192 waves.
// ---------------------------------------------------------------------------
__global__ __launch_bounds__(256) void knn_partial_kernel(
    const float4* __restrict__ spacked, const int* __restrict__ soidx,
    u64* __restrict__ pkey) {
  const int s = blockIdx.x % SPLIT;
  const int ntile = (blockIdx.x / SPLIT) % (NPTS / PTILE);
  const int b = blockIdx.x / (SPLIT * (NPTS / PTILE));
  const int p = threadIdx.x & (PTILE - 1);
  const int q4 = threadIdx.x >> 6;  // quarter 0..3 == wave id
  __shared__ u64 ubuf[1024];        // 8 KB: u8 scratch(6K) ∪ staging[16][64]

  const float4* sp4 = spacked + (size_t)b * NPTS;
  const int* sid = soidx + (size_t)b * NPTS;
  const int wbase = ntile * PTILE;
  const int pos = wbase + p;
  float4 pp = sp4[pos];
  const float ppx = pp.x, ppy = pp.y, ppz = pp.z, psq = pp.w;

  // wave-uniform candidate sub-window base
  const int qLo =
      __builtin_amdgcn_readfirstlane(win_lo(wbase) + s * WQ + q4 * QCH);
  const float4* win = sp4 + qLo;
  const int* wid = sid + qLo;

  // ---- Phase 1: top-16 packed keys + exact 17th (r17) ----
  int T[16];
#pragma unroll
  for (int i = 0; i < 16; ++i) T[i] = 0x7FFFFFFF;  // sentinel > any real key
  int r17 = 0x7FFFFFFF;

#pragma unroll 1
  for (int base = 0; base < QCH; base += 16) {
    int A[16];
#pragma unroll
    for (int t = 0; t < 16; ++t) {
      float4 q = win[base + t];  // uniform addr -> broadcast
      int bits = __float_as_int(d2_ref(q, ppx, ppy, ppz, psq));
      A[t] = (bits & 0xFFFFFF00) | (base + t);
    }
    batcher_sort16_i32(A);
    int u[16];
#pragma unroll
    for (int i = 0; i < 16; ++i) u[i] = max(T[i], A[15 - i]);
#pragma unroll
    for (int w = 8; w > 0; w >>= 1) {
#pragma unroll
      for (int i = 0; i < 16; ++i) {
        if (i < w) u[i] = min(u[i], u[i + w]);
      }
    }
    r17 = min(r17, u[0]);
    merge_keep16_i32(T, A);
  }

  const int tau = T[15] & 0xFFFFFF00;
  const bool slow = ((r17 & 0xFFFFFF00) == tau);

  // ---- Epilogue: exact u64 top-16 keys (original indices) ----
  u64 K[16];
  if (!slow) {
#pragma unroll
    for (int j = 0; j < 16; ++j) {
      int loc = T[j] & 255;  // < QCH
      float4 q = win[loc];
      float d2 = d2_ref(q, ppx, ppy, ppz, psq);
      K[j] = pack_key(d2, wid[loc]);
    }
    batcher_sort16_u64(K);
  } else {
    unsigned char* myb =
        reinterpret_cast<unsigned char*>(ubuf) + (unsigned)threadIdx.x * EPC;
    int cnt = 0;
#pragma unroll 4
    for (int m = 0; m < QCH; ++m) {
      float4 q = win[m];  // uniform
      int tb = __float_as_int(d2_ref(q, ppx, ppy, ppz, psq)) & 0xFFFFFF00;
      if (tb <= tau) {
        myb[cnt < EPC - 1 ? cnt : EPC - 1] = (unsigned char)m;
        ++cnt;
      }
    }
    u64 KK[32];
#pragma unroll
    for (int j = 0; j < EPC; ++j) {
      int loc = min((int)myb[j], QCH - 1);
      float4 q = win[loc];
      float d2 = d2_ref(q, ppx, ppy, ppz, psq);
      u64 k = pack_key(d2, wid[loc]);
      KK[j] = (j < cnt) ? k : ~0ull;
    }
#pragma unroll
    for (int j = EPC; j < 32; ++j) KK[j] = ~0ull;
    bitonic_sort32(KK);
#pragma unroll
    for (int j = 0; j < 16; ++j) K[j] = KK[j];
  }

  // ---- combine quarters: chain q1,q2,q3 stage -> q0 merges (R12-proven) ----
  __syncthreads();
  u64(*L)[PTILE] = reinterpret_cast<u64(*)[PTILE]>(ubuf);  // [16][64]
#pragma unroll 1
  for (int r = 1; r <= 3; ++r) {
    if (q4 == r) {
#pragma unroll
      for (int j = 0; j < 16; ++j) L[j][p] = K[j];
    }
    __syncthreads();
    if (q4 == 0) {
      u64 A64[16];
#pragma unroll
      for (int j = 0; j < 16; ++j) A64[j] = L[j][p];
      merge_keep16(K, A64);
    }
    __syncthreads();
  }
  if (q4 == 0) {
    u64* pb = pkey + ((size_t)(b * SPLIT + s) * KNN) * NPTS + pos;
#pragma unroll
    for (int j = 0; j < 16; ++j) pb[(size_t)j * NPTS] = K[j];
  }
}

// ---------------------------------------------------------------------------
// Kernel 1b: merge SPLIT window-quarter lists -> window top-16, slab-check
// the window boundaries (R14/R15-validated exactness test), flag failures,
// score. R10/R12's proven 4-threads-per-point form. n = SORTED position.
// grid: BATCH*(NPTS/64) = 512 blocks x 256.
// ---------------------------------------------------------------------------
__global__ __launch_bounds__(256) void merge_score_kernel(
    const float* __restrict__ x, const float4* __restrict__ spacked,
    const int* __restrict__ soidx, const u64* __restrict__ pkey,
    float* __restrict__ score, int* __restrict__ flagcnt,
    int* __restrict__ flaglist) {
  const int tile = blockIdx.x % (NPTS / 64);
  const int b = blockIdx.x / (NPTS / 64);
  const int g = threadIdx.x >> 2;  // point within tile [0,64)
  const int s = threadIdx.x & 3;   // split list
  const int n = tile * 64 + g;     // sorted position

  u64 T[16];
  {
    const u64* pb = pkey + ((size_t)(b * SPLIT + s) * KNN) * NPTS + n;
#pragma unroll
    for (int j = 0; j < 16; ++j) T[j] = pb[(size_t)j * NPTS];
  }
  u64 A[16];
#pragma unroll
  for (int j = 0; j < 16; ++j) A[j] = (u64)__shfl_xor((long long)T[j], 1);
  merge_keep16(T, A);
#pragma unroll
  for (int j = 0; j < 16; ++j) A[j] = (u64)__shfl_xor((long long)T[j], 2);
  merge_keep16(T, A);
  // all 4 lanes hold the window's sorted top-16 (exact, original indices).

  const float4* sp4 = spacked + (size_t)b * NPTS;
  const int orig = soidx[(size_t)b * NPTS + n];

  // ---- window-sufficiency slab test (exact; see R14/R15 proof) ----
  const int wlo = win_lo(n & ~(PTILE - 1));
  const int whi = wlo + WIN;
  const float xn = sp4[n].x;
  const float bnd = key_d2(T[15]);
  bool safe = true;
  if (wlo > 0) {
    float dx = xn - sp4[wlo - 1].x;  // >= 0 (sorted)
    safe = safe && (dx * dx > bnd + MARGIN);
  }
  if (whi < NPTS) {
    float dx = sp4[whi].x - xn;  // >= 0
    safe = safe && (dx * dx > bnd + MARGIN);
  }
  if (!safe && s == 0) {
    int idx = atomicAdd(flagcnt, 1);
    flaglist[idx] = (b << 12) | n;
  }

  // ---- score (numpy pairwise; lanes 0..2 own dims; recombine) ----
  const float* xb = x + (size_t)b * 3 * NPTS;
  float P = 0.0f;
  if (s < 3) {
    const float* xd = xb + (size_t)s * NPTS;
    const float pc = xd[orig];
    float r[8];
#pragma unroll
    for (int j = 0; j < 8; ++j) {
      float c0 = xd[(int)(unsigned)T[j]];
      float c1 = xd[(int)(unsigned)T[j + 8]];
      float e0 = __fsub_rn(c0, pc);
      float e1 = __fsub_rn(c1, pc);
      r[j] = __fadd_rn(__fmul_rn(e0, e0), __fmul_rn(e1, e1));
    }
    float t0 = __fadd_rn(r[0], r[1]);
    float t1 = __fadd_rn(r[2], r[3]);
    float t2 = __fadd_rn(r[4], r[5]);
    float t3 = __fadd_rn(r[6], r[7]);
    P = __fadd_rn(__fadd_rn(t0, t1), __fadd_rn(t2, t3));
  }
  float Pa = __shfl_xor(P, 1);
  float Pb = __shfl_xor(P, 2);
  if (s == 0)
    score[(size_t)b * NPTS + orig] = __fadd_rn(__fadd_rn(P, Pa), Pb);
}

// ---------------------------------------------------------------------------
// Kernel 1c (fixup): one WAVE per flagged point, exact full-batch scan
// (64 lanes x 64 cands, exact u64 keys) + log-merge; lane 0 rescores.
// R16 lesson: at 64 blocks this starved (0.25 waves/SIMD, 248us for ~10K
// flagged points). Grid now FIXBLK=1024 blocks = 4096 waves (stride loop).
// ---------------------------------------------------------------------------
__global__ __launch_bounds__(256) void fixup_kernel(
    const float* __restrict__ x, const float4* __restrict__ spacked,
    const int* __restrict__ soidx, const int* __restrict__ flagcnt,
    const int* __restrict__ flaglist, float* __restrict__ score) {
  const int wave = (blockIdx.x * 256 + threadIdx.x) >> 6;
  const int lane = threadIdx.x & 63;
  const int nwaves = FIXBLK * 4;
  const int cnt = *flagcnt;
#pragma unroll 1
  for (int i = wave; i < cnt; i += nwaves) {
    int e = flaglist[i];
    int b = e >> 12;
    int pos = e & (NPTS - 1);
    const float4* sp4 = spacked + (size_t)b * NPTS;
    const int* sid = soidx + (size_t)b * NPTS;
    float4 pp = sp4[pos];
    const float ppx = pp.x, ppy = pp.y, ppz = pp.z, psq = pp.w;

    u64 T[16];
#pragma unroll
    for (int j = 0; j < 16; ++j) T[j] = ~0ull;
#pragma unroll 1
    for (int k = 0; k < 4; ++k) {
      int s0 = lane * 16 + k * 1024;  // all 4096 covered exactly once
      u64 A[16];
#pragma unroll
      for (int t = 0; t < 16; ++t) {
        float4 q = sp4[s0 + t];
        float d2 = d2_ref(q, ppx, ppy, ppz, psq);
        A[t] = pack_key(d2, sid[s0 + t]);
      }
      batcher_sort16_u64(A);
      merge_keep16(T, A);
    }
#pragma unroll
    for (int m = 1; m <= 32; m <<= 1) {
      u64 A[16];
#pragma unroll
      for (int j = 0; j < 16; ++j) A[j] = (u64)__shfl_xor((long long)T[j], m);
      merge_keep16(T, A);
    }
    if (lane == 0) {
      const float* xb = x + (size_t)b * 3 * NPTS;
      const int orig = sid[pos];
      float P[3];
#pragma unroll
      for (int d = 0; d < 3; ++d) {
        const float* xd = xb + (size_t)d * NPTS;
        const float pc = xd[orig];
        float r[8];
#pragma unroll
        for (int j = 0; j < 8; ++j) {
          float c0 = xd[(int)(unsigned)T[j]];
          float c1 = xd[(int)(unsigned)T[j + 8]];
          float e0 = __fsub_rn(c0, pc);
          float e1 = __fsub_rn(c1, pc);
          r[j] = __fadd_rn(__fmul_rn(e0, e0), __fmul_rn(e1, e1));
        }
        float t0 = __fadd_rn(r[0], r[1]);
        float t1 = __fadd_rn(r[2], r[3]);
        float t2 = __fadd_rn(r[4], r[5]);
        float t3 = __fadd_rn(r[6], r[7]);
        P[d] = __fadd_rn(__fadd_rn(t0, t1), __fadd_rn(t2, t3));
      }
      score[(size_t)b * NPTS + orig] =
          __fadd_rn(__fadd_rn(P[0], P[1]), P[2]);
    }
  }
}

// ---------------------------------------------------------------------------
// Kernel 2 (fused rank + scatter, atomics-free; R11-proven).
// grid: BATCH*(NPTS/128) = 256 blocks.
// ---------------------------------------------------------------------------
__global__ __launch_bounds__(256) void rank_scatter_kernel(
    const float* __restrict__ score, int* __restrict__ sel, int npts) {
  const int tile = blockIdx.x % (NPTS / 128);
  const int b = blockIdx.x / (NPTS / 128);
  const int p = threadIdx.x & 127;
  const int h = threadIdx.x >> 7;
  __shared__ float4 sv[NPTS / 4];  // 16 KB
  __shared__ int cpart[128];

  const float* sb = score + (size_t)b * NPTS;
  const float4* sb4 = reinterpret_cast<const float4*>(sb);
  for (int i = threadIdx.x; i < NPTS / 4; i += 256) sv[i] = sb4[i];

  const int n = tile * 128 + p;
  const float sn = sb[n];
  __syncthreads();

  int c = 0;
  const int v0 = h * (NPTS / 8);
#pragma unroll 4
  for (int v = v0; v < v0 + NPTS / 8; ++v) {
    float4 f = sv[v];
    int gm = 4 * v;
    c += (f.x > sn) || (f.x == sn && gm < n);
    c += (f.y > sn) || (f.y == sn && gm + 1 < n);
    c += (f.z > sn) || (f.z == sn && gm + 2 < n);
    c += (f.w > sn) || (f.w == sn && gm + 3 < n);
  }
  if (h == 1) cpart[p] = c;
  __syncthreads();
  if (h == 0) {
    c += cpart[p];
    if (c < npts) sel[(size_t)b * npts + c] = n;
  }
}

// ---------------------------------------------------------------------------
// Kernel 3: gather xyz then features into the concatenated flat output.
// ---------------------------------------------------------------------------
__global__ __launch_bounds__(256) void gather_kernel(
    const float* __restrict__ x, const float* __restrict__ y,
    const int* __restrict__ sel, float* __restrict__ out, int npts,
    int total0, int total) {
  int tid = blockIdx.x * blockDim.x + threadIdx.x;
  if (tid >= total) return;
  if (tid < total0) {
    int j = tid % npts;
    int rest = tid / npts;
    int d = rest % 3;
    int b = rest / 3;
    int src = sel[b * npts + j];
    out[tid] = x[((size_t)b * 3 + d) * NPTS + src];
  } else {
    int t = tid - total0;
    int j = t % npts;
    int rest = t / npts;
    int c = rest % CHAN;
    int b = rest / CHAN;
    int src = sel[b * npts + j];
    out[tid] = y[((size_t)b * CHAN + c) * NPTS + src];
  }
}

extern "C" void kernel_launch(void* const* d_in, const int* in_sizes, int n_in,
                              void* d_out, int out_size, void* d_ws,
                              size_t ws_size, hipStream_t stream) {
  const float* x = (const float*)d_in[0];
  const float* y = (const float*)d_in[1];
  float* out = (float*)d_out;

  const int npts = out_size / (BATCH * (3 + CHAN));

  // workspace layout (~19.3 MB):
  char* w = (char*)d_ws;
  float4* spacked = (float4*)w;              // B*N float4 = 2 MB (x-sorted)
  w += sizeof(float4) * (size_t)BATCH * NPTS;
  int* soidx = (int*)w;                      // B*N i32 (sorted -> original)
  w += sizeof(int) * (size_t)BATCH * NPTS;
  u64* pkey = (u64*)w;                       // B*S*16*N u64 = 16.78 MB
  w += sizeof(u64) * (size_t)BATCH * SPLIT * KNN * NPTS;
  float* score = (float*)w;                  // B*N f32
  w += sizeof(float) * (size_t)BATCH * NPTS;
  int* flagcnt = (int*)w;                    // 1 i32 (+ pad)
  w += 256;
  int* flaglist = (int*)w;                   // B*N i32 worst case
  w += sizeof(int) * (size_t)BATCH * NPTS;
  int* sel = (int*)w;                        // B*npts i32

  xsort_kernel<<<BATCH * (NPTS / 64), 256, 0, stream>>>(x, spacked, soidx,
                                                        flagcnt);
  knn_partial_kernel<<<BATCH * (NPTS / PTILE) * SPLIT, 256, 0, stream>>>(
      spacked, soidx, pkey);
  merge_score_kernel<<<BATCH * (NPTS / 64), 256, 0, stream>>>(
      x, spacked, soidx, pkey, score, flagcnt, flaglist);
  fixup_kernel<<<FIXBLK, 256, 0, stream>>>(x, spacked, soidx, flagcnt,
                                           flaglist, score);
  rank_scatter_kernel<<<BATCH * (NPTS / 128), 256, 0, stream>>>(score, sel,
                                                                npts);
  const int total0 = BATCH * 3 * npts;
  gather_kernel<<<(out_size + 255) / 256, 256, 0, stream>>>(
      x, y, sel, out, npts, total0, out_size);
}